// Round 4
// baseline (399.844 us; speedup 1.0000x reference)
//
#include <hip/hip_runtime.h>
#include <hip/hip_bf16.h>
#include <math.h>

#define BB 8
#define NN 200000
#define CC 81
#define TOPK 200
#define CAP 4096
#define NBIN 4096

static __device__ __forceinline__ int bin_of(unsigned key) {
    // score in [1/81, 1] -> exponent in [120,127]; bits above bit 25 constant.
    // 12-bit monotone bin: exp low-3 bits + top-9 mantissa bits.
    return (int)((key >> 14) & (NBIN - 1));
}

// ---------------------------------------------------------------------------
// Kernel Z: zero hist (BB*NBIN words) + cnt (BB words).
// ---------------------------------------------------------------------------
__global__ __launch_bounds__(256) void zero_kernel(unsigned* __restrict__ hist_and_cnt,
                                                   int nwords) {
    int i = blockIdx.x * 256 + threadIdx.x;
    if (i < nwords) hist_and_cnt[i] = 0u;
}

// ---------------------------------------------------------------------------
// Kernel A (fused): scores[p] = 1/sum_c exp(logits[p,c]-max_c) AND per-batch
// 4096-bin histogram of the score keys (LDS hist per block, flush nonzero).
// grid = (NN/64, BB), block = 1024 (16 waves x 4 rows = 64 rows/block).
// ---------------------------------------------------------------------------
__global__ __launch_bounds__(1024) void scores_hist_kernel(const float* __restrict__ logits,
                                                           float* __restrict__ scores,
                                                           unsigned* __restrict__ hist) {
    __shared__ unsigned h[NBIN];
    int tid = threadIdx.x;
    int b = blockIdx.y;
    for (int i = tid; i < NBIN; i += 1024) h[i] = 0u;
    __syncthreads();

    int wave = tid >> 6;
    int lane = tid & 63;
    int group = lane >> 4;
    int sub = lane & 15;
    int r = blockIdx.x * 64 + wave * 4 + group;   // 3125*64 == NN exactly
    const float* row = logits + ((size_t)b * NN + r) * CC;

    float m = -INFINITY;
#pragma unroll
    for (int j = 0; j < 6; ++j) {
        int c = sub + j * 16;
        if (c < CC) m = fmaxf(m, row[c]);
    }
#pragma unroll
    for (int w = 1; w < 16; w <<= 1) m = fmaxf(m, __shfl_xor(m, w, 64));

    float ss = 0.0f;
#pragma unroll
    for (int j = 0; j < 6; ++j) {
        int c = sub + j * 16;
        if (c < CC) ss += expf(row[c] - m);
    }
#pragma unroll
    for (int w = 1; w < 16; w <<= 1) ss += __shfl_xor(ss, w, 64);

    if (sub == 0) {
        float s = 1.0f / ss;
        scores[(size_t)b * NN + r] = s;
        atomicAdd(&h[bin_of(__float_as_uint(s))], 1u);
    }
    __syncthreads();

    unsigned* gh = hist + (size_t)b * NBIN;
    for (int i = tid; i < NBIN; i += 1024) {
        unsigned c = h[i];
        if (c) atomicAdd(&gh[i], c);
    }
}

// ---------------------------------------------------------------------------
// Kernel C: per-batch threshold bin = highest bin where cumulative (from top)
// count >= TOPK. One block per batch.
// ---------------------------------------------------------------------------
__global__ __launch_bounds__(256) void thresh_kernel(const unsigned* __restrict__ hist,
                                                     int* __restrict__ thresh) {
    __shared__ unsigned csum[256];
    int tid = threadIdx.x;
    int b = blockIdx.x;
    const unsigned* gh = hist + (size_t)b * NBIN;
    int hi = NBIN - 1 - 16 * tid;
    unsigned s = 0;
#pragma unroll
    for (int j = 0; j < 16; ++j) s += gh[hi - j];
    csum[tid] = s;
    __syncthreads();
    if (tid == 0) {
        unsigned run = 0;
        for (int t = 0; t < 256; ++t) { unsigned tmp = csum[t]; csum[t] = run; run += tmp; }
    }
    __syncthreads();
    unsigned before = csum[tid];
    if (before < TOPK && before + s >= TOPK) {
        unsigned cum = before;
        for (int j = 0; j < 16; ++j) {
            cum += gh[hi - j];
            if (cum >= TOPK) { thresh[b] = hi - j; break; }
        }
    }
}

// ---------------------------------------------------------------------------
// Kernel D: compact candidate indices (bin >= thresh) per batch
// ---------------------------------------------------------------------------
__global__ __launch_bounds__(256) void compact_kernel(const float* __restrict__ scores,
                                                      const int* __restrict__ thresh,
                                                      int* __restrict__ cand,
                                                      int* __restrict__ cnt) {
    int b = blockIdx.y;
    int t = thresh[b];
    const float* sc = scores + (size_t)b * NN;
    for (int i = blockIdx.x * 256 + threadIdx.x; i < NN; i += gridDim.x * 256) {
        unsigned key = __float_as_uint(sc[i]);
        if (bin_of(key) >= t) {
            int pos = atomicAdd(&cnt[b], 1);
            if (pos < CAP) cand[(size_t)b * CAP + pos] = i;
        }
    }
}

// ---------------------------------------------------------------------------
// Kernel E: exact top-200 by (key desc, idx desc) rank among candidates
// (== stable ascending argsort, take last 200), then greedy NMS
// (argmax tie -> smallest index) with packed-u64 wave reduce. 1 block/batch.
// ---------------------------------------------------------------------------
__global__ __launch_bounds__(1024) void final_kernel(const float* __restrict__ scores,
                                                     const float* __restrict__ segs,
                                                     const int* __restrict__ cand,
                                                     const int* __restrict__ cnt,
                                                     int* __restrict__ out) {
    __shared__ unsigned k_key[CAP];
    __shared__ int k_idx[CAP];
    __shared__ float sel_x1[TOPK], sel_x2[TOPK];
    __shared__ unsigned sel_k[TOPK];
    __shared__ int sel_i[TOPK];

    int b = blockIdx.x;
    int tid = threadIdx.x;
    const float* sc = scores + (size_t)b * NN;
    const float* sg = segs + (size_t)b * NN * 2;
    int M = cnt[b]; if (M > CAP) M = CAP;

    for (int j = tid; j < M; j += 1024) {
        int idx = cand[(size_t)b * CAP + j];
        k_idx[j] = idx;
        k_key[j] = __float_as_uint(sc[idx]);
    }
    for (int i = tid; i < TOPK; i += 1024) out[(BB + b) * TOPK + i] = 0;
    __syncthreads();

    for (int j = tid; j < M; j += 1024) {
        unsigned kj = k_key[j];
        int ij = k_idx[j];
        int rank = 0;
        for (int m = 0; m < M; ++m) {
            unsigned km = k_key[m];
            rank += (km > kj) || (km == kj && k_idx[m] > ij);
        }
        if (rank < TOPK) {
            sel_k[rank] = kj;
            sel_i[rank] = ij;
            sel_x1[rank] = sg[2 * (size_t)ij];
            sel_x2[rank] = sg[2 * (size_t)ij + 1];
        }
    }
    __syncthreads();

    if (tid >= 64) return;
    int lane = tid;
    // packed key: hi32 = score bits (positive float, monotone), lo32 = ~idx
    // (so bigger packed == higher score, then smaller index). 0 == inactive.
    unsigned long long pk[4];
    float rx1[4], rx2[4];
    int ridx[4];
#pragma unroll
    for (int k = 0; k < 4; ++k) {
        int c = k * 64 + lane;
        if (c < TOPK) {
            pk[k] = ((unsigned long long)sel_k[c] << 32) | (unsigned)(~sel_i[c]);
            rx1[k] = sel_x1[c]; rx2[k] = sel_x2[c]; ridx[k] = sel_i[c];
        } else {
            pk[k] = 0ull; rx1[k] = 0.f; rx2[k] = 0.f; ridx[k] = -1;
        }
    }

    int* keep = out + b * TOPK;
    int it = 0;
    for (; it < TOPK; ++it) {
        unsigned long long best = 0ull;
#pragma unroll
        for (int k = 0; k < 4; ++k) if (pk[k] > best) best = pk[k];
#pragma unroll
        for (int w = 1; w < 64; w <<= 1) {
            unsigned long long o = __shfl_xor(best, w, 64);
            if (o > best) best = o;
        }
        if (best == 0ull) break;
        int bidx = (int)(~(unsigned)(best & 0xffffffffull));
        if (lane == 0) keep[it] = bidx;

        float wx1 = 0.f, wx2 = 0.f;
        bool have = false;
#pragma unroll
        for (int k = 0; k < 4; ++k) {
            if (pk[k] != 0ull && ridx[k] == bidx) {
                wx1 = rx1[k]; wx2 = rx2[k]; have = true; pk[k] = 0ull;
            }
        }
        unsigned long long bm = __ballot(have);
        int src = __ffsll(bm) - 1;
        wx1 = __shfl(wx1, src, 64);
        wx2 = __shfl(wx2, src, 64);
#pragma unroll
        for (int k = 0; k < 4; ++k) {
            if (pk[k] != 0ull) {
                float inter = fminf(rx2[k], wx2) - fmaxf(rx1[k], wx1);
                if (inter > 0.f) pk[k] = 0ull;
            }
        }
    }
    for (int j = it + lane; j < TOPK; j += 64) keep[j] = 0;
}

extern "C" void kernel_launch(void* const* d_in, const int* in_sizes, int n_in,
                              void* d_out, int out_size, void* d_ws, size_t ws_size,
                              hipStream_t stream) {
    const float* logits = (const float*)d_in[0];   // (8, 200000, 81) f32
    const float* segs   = (const float*)d_in[1];   // (8, 200000, 2)  f32
    int* out = (int*)d_out;                        // (16, 200) int32

    // ws layout
    char* ws = (char*)d_ws;
    float*    scores = (float*)ws;                                  // 6,400,000 B
    unsigned* hist   = (unsigned*)(ws + 6400000);                   // 131,072 B
    int*      cnt    = (int*)(ws + 6400000 + 131072);               // 32 B
    int*      thresh = (int*)(ws + 6400000 + 131072 + 32);          // 32 B
    int*      cand   = (int*)(ws + 6400000 + 131072 + 64);          // 131,072 B

    // zero hist + cnt (contiguous: NBIN*BB + BB words)
    int nwords = NBIN * BB + BB;
    zero_kernel<<<(nwords + 255) / 256, 256, 0, stream>>>(hist, nwords);

    dim3 sgrid(NN / 64, BB);                       // 3125 x 8, 64 rows/block
    scores_hist_kernel<<<sgrid, 1024, 0, stream>>>(logits, scores, hist);

    thresh_kernel<<<BB, 256, 0, stream>>>(hist, thresh);
    dim3 cgrid(128, BB);
    compact_kernel<<<cgrid, 256, 0, stream>>>(scores, thresh, cand, cnt);
    final_kernel<<<BB, 1024, 0, stream>>>(scores, segs, cand, cnt, out);
}

// Round 5
// 230.123 us; speedup vs baseline: 1.7375x; 1.7375x over previous
//
#include <hip/hip_runtime.h>
#include <hip/hip_bf16.h>
#include <math.h>

#define BB 8
#define NN 200000
#define CC 81
#define TOPK 200
#define CAP 4096
#define NBIN 4096

static __device__ __forceinline__ int bin_of(unsigned key) {
    // score in [1/81, 1] -> exponent in [120,127]; bits above bit 25 constant.
    // 12-bit monotone bin: exp low-3 bits + top-9 mantissa bits.
    return (int)((key >> 14) & (NBIN - 1));
}

// ---------------------------------------------------------------------------
// Kernel A: scores[p] = 1/sum_c exp(logits[p,c]-max_c). LDS-staged:
// 64 rows/block (20.7KB) loaded as 1296 aligned float4s (fully coalesced),
// then the identical 16-lane-group reduction as the passing version.
// grid = (NN/64, BB) = (3125, 8), block = 256.
// ---------------------------------------------------------------------------
__global__ __launch_bounds__(256) void scores_kernel(const float* __restrict__ logits,
                                                     float* __restrict__ scores) {
    __shared__ float ls[64 * CC];     // 5184 floats = 20.7 KB
    __shared__ float lsc[64];
    int tid = threadIdx.x;
    int b = blockIdx.y;
    size_t fbase = ((size_t)b * NN + (size_t)blockIdx.x * 64) * CC;  // 16B-aligned
    const float4* g4 = (const float4*)(logits + fbase);
    float4* l4 = (float4*)ls;
    for (int t = tid; t < (64 * CC) / 4; t += 256) l4[t] = g4[t];
    __syncthreads();

    int wave = tid >> 6;
    int lane = tid & 63;
    int group = lane >> 4;
    int sub = lane & 15;

#pragma unroll
    for (int pass = 0; pass < 4; ++pass) {
        int lr = pass * 16 + wave * 4 + group;   // 0..63
        const float* row = ls + lr * CC;

        float m = -INFINITY;
#pragma unroll
        for (int j = 0; j < 6; ++j) {
            int c = sub + j * 16;
            if (c < CC) m = fmaxf(m, row[c]);
        }
#pragma unroll
        for (int w = 1; w < 16; w <<= 1) m = fmaxf(m, __shfl_xor(m, w, 64));

        float ss = 0.0f;
#pragma unroll
        for (int j = 0; j < 6; ++j) {
            int c = sub + j * 16;
            if (c < CC) ss += expf(row[c] - m);
        }
#pragma unroll
        for (int w = 1; w < 16; w <<= 1) ss += __shfl_xor(ss, w, 64);

        if (sub == 0) lsc[lr] = 1.0f / ss;
    }
    __syncthreads();
    if (tid < 64) scores[(size_t)b * NN + (size_t)blockIdx.x * 64 + tid] = lsc[tid];
}

// ---------------------------------------------------------------------------
// Kernel B (tail, one block per batch, 1024 threads):
//   1) LDS 4096-bin histogram of all 200k score keys (float4 reads)
//   2) exact rank-200 threshold bin
//   3) gather candidates (bin >= t) into LDS
//   4) exact top-200 by (key desc, idx desc)  == stable argsort tail rule
//   5) greedy NMS (tie -> smallest index) with packed-u64 wave reduce
// ---------------------------------------------------------------------------
__global__ __launch_bounds__(1024) void tail_kernel(const float* __restrict__ scores,
                                                    const float* __restrict__ segs,
                                                    int* __restrict__ out) {
    __shared__ unsigned h[NBIN];
    __shared__ unsigned csum[256];
    __shared__ int s_t, s_cnt;
    __shared__ unsigned k_key[CAP];
    __shared__ int k_idx[CAP];
    __shared__ unsigned sel_k[TOPK];
    __shared__ int sel_i[TOPK];
    __shared__ float sel_x1[TOPK], sel_x2[TOPK];

    int b = blockIdx.x;
    int tid = threadIdx.x;
    const float* sc = scores + (size_t)b * NN;
    const float* sg = segs + (size_t)b * NN * 2;

    for (int i = tid; i < NBIN; i += 1024) h[i] = 0u;
    if (tid == 0) s_cnt = 0;
    for (int i = tid; i < TOPK; i += 1024) out[(BB + b) * TOPK + i] = 0;
    __syncthreads();

    // --- 1) histogram (200k LDS atomics amortize the 4096-bin overhead) ---
    const float4* sc4 = (const float4*)sc;
    for (int i = tid; i < NN / 4; i += 1024) {
        float4 v = sc4[i];
        atomicAdd(&h[bin_of(__float_as_uint(v.x))], 1u);
        atomicAdd(&h[bin_of(__float_as_uint(v.y))], 1u);
        atomicAdd(&h[bin_of(__float_as_uint(v.z))], 1u);
        atomicAdd(&h[bin_of(__float_as_uint(v.w))], 1u);
    }
    __syncthreads();

    // --- 2) threshold: highest bin with cumulative-from-top >= TOPK ---
    unsigned s = 0;
    int hi = 0;
    if (tid < 256) {
        hi = NBIN - 1 - 16 * tid;
#pragma unroll
        for (int j = 0; j < 16; ++j) s += h[hi - j];
        csum[tid] = s;
    }
    __syncthreads();
    if (tid == 0) {
        unsigned run = 0;
        for (int t = 0; t < 256; ++t) { unsigned tmp = csum[t]; csum[t] = run; run += tmp; }
    }
    __syncthreads();
    if (tid < 256) {
        unsigned before = csum[tid];
        if (before < TOPK && before + s >= TOPK) {
            unsigned cum = before;
            for (int j = 0; j < 16; ++j) {
                cum += h[hi - j];
                if (cum >= TOPK) { s_t = hi - j; break; }
            }
        }
    }
    __syncthreads();
    int t = s_t;

    // --- 3) gather candidates (second pass, L2-hot) ---
    for (int i = tid; i < NN / 4; i += 1024) {
        float4 v = sc4[i];
        unsigned keys[4] = { __float_as_uint(v.x), __float_as_uint(v.y),
                             __float_as_uint(v.z), __float_as_uint(v.w) };
#pragma unroll
        for (int j = 0; j < 4; ++j) {
            if (bin_of(keys[j]) >= t) {
                int pos = atomicAdd(&s_cnt, 1);
                if (pos < CAP) { k_key[pos] = keys[j]; k_idx[pos] = 4 * i + j; }
            }
        }
    }
    __syncthreads();
    int M = s_cnt; if (M > CAP) M = CAP;

    // --- 4) exact top-200 by (key desc, idx desc) ---
    for (int j = tid; j < M; j += 1024) {
        unsigned kj = k_key[j];
        int ij = k_idx[j];
        int rank = 0;
        for (int m = 0; m < M; ++m) {
            unsigned km = k_key[m];
            rank += (km > kj) || (km == kj && k_idx[m] > ij);
        }
        if (rank < TOPK) {
            sel_k[rank] = kj;
            sel_i[rank] = ij;
            sel_x1[rank] = sg[2 * (size_t)ij];
            sel_x2[rank] = sg[2 * (size_t)ij + 1];
        }
    }
    __syncthreads();

    // --- 5) greedy NMS on wave 0; packed (score, ~idx) u64 max reduce ---
    if (tid >= 64) return;
    int lane = tid;
    unsigned long long pk[4];
    float rx1[4], rx2[4];
    int ridx[4];
#pragma unroll
    for (int k = 0; k < 4; ++k) {
        int c = k * 64 + lane;
        if (c < TOPK) {
            pk[k] = ((unsigned long long)sel_k[c] << 32) | (unsigned)(~sel_i[c]);
            rx1[k] = sel_x1[c]; rx2[k] = sel_x2[c]; ridx[k] = sel_i[c];
        } else {
            pk[k] = 0ull; rx1[k] = 0.f; rx2[k] = 0.f; ridx[k] = -1;
        }
    }

    int* keep = out + b * TOPK;
    int it = 0;
    for (; it < TOPK; ++it) {
        unsigned long long best = 0ull;
#pragma unroll
        for (int k = 0; k < 4; ++k) if (pk[k] > best) best = pk[k];
#pragma unroll
        for (int w = 1; w < 64; w <<= 1) {
            unsigned long long o = __shfl_xor(best, w, 64);
            if (o > best) best = o;
        }
        if (best == 0ull) break;
        int bidx = (int)(~(unsigned)(best & 0xffffffffull));
        if (lane == 0) keep[it] = bidx;

        float wx1 = 0.f, wx2 = 0.f;
        bool have = false;
#pragma unroll
        for (int k = 0; k < 4; ++k) {
            if (pk[k] != 0ull && ridx[k] == bidx) {
                wx1 = rx1[k]; wx2 = rx2[k]; have = true; pk[k] = 0ull;
            }
        }
        unsigned long long bm = __ballot(have);
        int src = __ffsll(bm) - 1;
        wx1 = __shfl(wx1, src, 64);
        wx2 = __shfl(wx2, src, 64);
#pragma unroll
        for (int k = 0; k < 4; ++k) {
            if (pk[k] != 0ull) {
                float inter = fminf(rx2[k], wx2) - fmaxf(rx1[k], wx1);
                if (inter > 0.f) pk[k] = 0ull;
            }
        }
    }
    for (int j = it + lane; j < TOPK; j += 64) keep[j] = 0;
}

extern "C" void kernel_launch(void* const* d_in, const int* in_sizes, int n_in,
                              void* d_out, int out_size, void* d_ws, size_t ws_size,
                              hipStream_t stream) {
    const float* logits = (const float*)d_in[0];   // (8, 200000, 81) f32
    const float* segs   = (const float*)d_in[1];   // (8, 200000, 2)  f32
    int* out = (int*)d_out;                        // (16, 200) int32
    float* scores = (float*)d_ws;                  // 6.4 MB scratch

    dim3 sgrid(NN / 64, BB);                       // 3125 x 8
    scores_kernel<<<sgrid, 256, 0, stream>>>(logits, scores);
    tail_kernel<<<BB, 1024, 0, stream>>>(scores, segs, out);
}

// Round 6
// 206.983 us; speedup vs baseline: 1.9318x; 1.1118x over previous
//
#include <hip/hip_runtime.h>
#include <hip/hip_bf16.h>
#include <math.h>

#define BB 8
#define NN 200000
#define CC 81
#define TOPK 200
#define CAP 4096
#define NBIN 4096

static __device__ __forceinline__ int bin_of(unsigned key) {
    // score in [1/81, 1] -> exponent in [120,127]; bits above bit 25 constant.
    // 12-bit monotone bin: exp low-3 bits + top-9 mantissa bits.
    return (int)((key >> 14) & (NBIN - 1));
}

// ---------------------------------------------------------------------------
// Kernel A: scores[p] = 1/sum_c exp(logits[p,c]-max_c). LDS-staged:
// 64 rows/block (20.7KB) loaded as aligned float4s (fully coalesced),
// then 16-lane-group reduction. Bit-identical to the passing version.
// grid = (NN/64, BB) = (3125, 8), block = 256.
// ---------------------------------------------------------------------------
__global__ __launch_bounds__(256) void scores_kernel(const float* __restrict__ logits,
                                                     float* __restrict__ scores) {
    __shared__ float ls[64 * CC];     // 5184 floats = 20.7 KB
    __shared__ float lsc[64];
    int tid = threadIdx.x;
    int b = blockIdx.y;
    size_t fbase = ((size_t)b * NN + (size_t)blockIdx.x * 64) * CC;  // 16B-aligned
    const float4* g4 = (const float4*)(logits + fbase);
    float4* l4 = (float4*)ls;
    for (int t = tid; t < (64 * CC) / 4; t += 256) l4[t] = g4[t];
    __syncthreads();

    int wave = tid >> 6;
    int lane = tid & 63;
    int group = lane >> 4;
    int sub = lane & 15;

#pragma unroll
    for (int pass = 0; pass < 4; ++pass) {
        int lr = pass * 16 + wave * 4 + group;   // 0..63
        const float* row = ls + lr * CC;

        float m = -INFINITY;
#pragma unroll
        for (int j = 0; j < 6; ++j) {
            int c = sub + j * 16;
            if (c < CC) m = fmaxf(m, row[c]);
        }
#pragma unroll
        for (int w = 1; w < 16; w <<= 1) m = fmaxf(m, __shfl_xor(m, w, 64));

        float ss = 0.0f;
#pragma unroll
        for (int j = 0; j < 6; ++j) {
            int c = sub + j * 16;
            if (c < CC) ss += expf(row[c] - m);
        }
#pragma unroll
        for (int w = 1; w < 16; w <<= 1) ss += __shfl_xor(ss, w, 64);

        if (sub == 0) lsc[lr] = 1.0f / ss;
    }
    __syncthreads();
    if (tid < 64) scores[(size_t)b * NN + (size_t)blockIdx.x * 64 + tid] = lsc[tid];
}

// ---------------------------------------------------------------------------
// Kernel B (tail, one block per batch, 1024 threads):
//   1) LDS 4096-bin histogram of all 200k score keys
//   2) exact rank-200 threshold bin
//   3) gather candidates (bin >= t) into LDS
//   4) exact top-200 by (key desc, idx desc)  == stable argsort tail rule
//   4b) re-rank the 200 into NMS priority order (key desc, idx ASC)
//       == reference argmax tie rule. Winner each round = first active pos.
//   5) greedy NMS as 256-bit active-mask scan: ffs winner + ballot update.
//      No cross-lane reduce chain.
// ---------------------------------------------------------------------------
__global__ __launch_bounds__(1024) void tail_kernel(const float* __restrict__ scores,
                                                    const float* __restrict__ segs,
                                                    int* __restrict__ out) {
    __shared__ unsigned h[NBIN];
    __shared__ unsigned csum[256];
    __shared__ int s_t, s_cnt;
    __shared__ unsigned k_key[CAP];
    __shared__ int k_idx[CAP];
    __shared__ unsigned sel_k[TOPK];
    __shared__ int sel_i[TOPK];
    __shared__ int nms_i[TOPK];
    __shared__ float nms_x1[TOPK + 56], nms_x2[TOPK + 56];  // padded: pos<256 reads safe

    int b = blockIdx.x;
    int tid = threadIdx.x;
    const float* sc = scores + (size_t)b * NN;
    const float* sg = segs + (size_t)b * NN * 2;

    for (int i = tid; i < NBIN; i += 1024) h[i] = 0u;
    if (tid == 0) s_cnt = 0;
    // pre-zero both output rows for this batch (keep row + mirror row)
    for (int i = tid; i < TOPK; i += 1024) {
        out[b * TOPK + i] = 0;
        out[(BB + b) * TOPK + i] = 0;
    }
    for (int i = tid; i < 56; i += 1024) { nms_x1[TOPK + i] = 0.f; nms_x2[TOPK + i] = 0.f; }
    __syncthreads();

    // --- 1) histogram ---
    const float4* sc4 = (const float4*)sc;
    for (int i = tid; i < NN / 4; i += 1024) {
        float4 v = sc4[i];
        atomicAdd(&h[bin_of(__float_as_uint(v.x))], 1u);
        atomicAdd(&h[bin_of(__float_as_uint(v.y))], 1u);
        atomicAdd(&h[bin_of(__float_as_uint(v.z))], 1u);
        atomicAdd(&h[bin_of(__float_as_uint(v.w))], 1u);
    }
    __syncthreads();

    // --- 2) threshold: highest bin with cumulative-from-top >= TOPK ---
    unsigned s = 0;
    int hi = 0;
    if (tid < 256) {
        hi = NBIN - 1 - 16 * tid;
#pragma unroll
        for (int j = 0; j < 16; ++j) s += h[hi - j];
        csum[tid] = s;
    }
    __syncthreads();
    if (tid == 0) {
        unsigned run = 0;
        for (int t = 0; t < 256; ++t) { unsigned tmp = csum[t]; csum[t] = run; run += tmp; }
    }
    __syncthreads();
    if (tid < 256) {
        unsigned before = csum[tid];
        if (before < TOPK && before + s >= TOPK) {
            unsigned cum = before;
            for (int j = 0; j < 16; ++j) {
                cum += h[hi - j];
                if (cum >= TOPK) { s_t = hi - j; break; }
            }
        }
    }
    __syncthreads();
    int t = s_t;

    // --- 3) gather candidates (second pass, L2-hot) ---
    for (int i = tid; i < NN / 4; i += 1024) {
        float4 v = sc4[i];
        unsigned keys[4] = { __float_as_uint(v.x), __float_as_uint(v.y),
                             __float_as_uint(v.z), __float_as_uint(v.w) };
#pragma unroll
        for (int j = 0; j < 4; ++j) {
            if (bin_of(keys[j]) >= t) {
                int pos = atomicAdd(&s_cnt, 1);
                if (pos < CAP) { k_key[pos] = keys[j]; k_idx[pos] = 4 * i + j; }
            }
        }
    }
    __syncthreads();
    int M = s_cnt; if (M > CAP) M = CAP;   // M >= TOPK by threshold construction

    // --- 4) exact top-200 by (key desc, idx desc) ---
    for (int j = tid; j < M; j += 1024) {
        unsigned kj = k_key[j];
        int ij = k_idx[j];
        int rank = 0;
        for (int m = 0; m < M; ++m) {
            unsigned km = k_key[m];
            rank += (km > kj) || (km == kj && k_idx[m] > ij);
        }
        if (rank < TOPK) { sel_k[rank] = kj; sel_i[rank] = ij; }
    }
    __syncthreads();

    // --- 4b) re-rank into NMS priority order: (key desc, idx asc) ---
    if (tid < TOPK) {
        unsigned kj = sel_k[tid];
        int ij = sel_i[tid];
        int r2 = 0;
        for (int m = 0; m < TOPK; ++m) {
            unsigned km = sel_k[m];
            r2 += (km > kj) || (km == kj && sel_i[m] < ij);
        }
        nms_i[r2] = ij;
        nms_x1[r2] = sg[2 * (size_t)ij];
        nms_x2[r2] = sg[2 * (size_t)ij + 1];
    }
    __syncthreads();

    // --- 5) mask-scan NMS on wave 0 ---
    if (tid >= 64) return;
    int lane = tid;
    float rx1[4], rx2[4];
#pragma unroll
    for (int k = 0; k < 4; ++k) {
        rx1[k] = nms_x1[k * 64 + lane];   // pos >= TOPK reads padded zeros
        rx2[k] = nms_x2[k * 64 + lane];
    }
    // active mask: 200 bits = 3 full words + 8 bits
    unsigned long long m0 = ~0ull, m1 = ~0ull, m2 = ~0ull, m3 = 0xffull;

    int* keep = out + b * TOPK;
    for (int it = 0; it < TOPK; ++it) {
        int p;
        if (m0)      p = __ffsll(m0) - 1;
        else if (m1) p = 64 + __ffsll(m1) - 1;
        else if (m2) p = 128 + __ffsll(m2) - 1;
        else if (m3) p = 192 + __ffsll(m3) - 1;
        else break;

        float wx1 = nms_x1[p];   // LDS broadcast (uniform address)
        float wx2 = nms_x2[p];
        if (lane == 0) keep[it] = nms_i[p];

        unsigned long long mw[4] = { m0, m1, m2, m3 };
        unsigned long long nm[4];
#pragma unroll
        for (int k = 0; k < 4; ++k) {
            bool alive = (mw[k] >> lane) & 1ull;
            bool kill = false;
            if (alive) {
                int pos = k * 64 + lane;
                if (pos == p) kill = true;
                else {
                    float inter = fminf(rx2[k], wx2) - fmaxf(rx1[k], wx1);
                    kill = inter > 0.f;
                }
            }
            nm[k] = __ballot(alive && !kill);
        }
        m0 = nm[0]; m1 = nm[1]; m2 = nm[2]; m3 = nm[3];
    }
    // non-kept tail already zeroed by the pre-zero pass
}

extern "C" void kernel_launch(void* const* d_in, const int* in_sizes, int n_in,
                              void* d_out, int out_size, void* d_ws, size_t ws_size,
                              hipStream_t stream) {
    const float* logits = (const float*)d_in[0];   // (8, 200000, 81) f32
    const float* segs   = (const float*)d_in[1];   // (8, 200000, 2)  f32
    int* out = (int*)d_out;                        // (16, 200) int32
    float* scores = (float*)d_ws;                  // 6.4 MB scratch

    dim3 sgrid(NN / 64, BB);                       // 3125 x 8
    scores_kernel<<<sgrid, 256, 0, stream>>>(logits, scores);
    tail_kernel<<<BB, 1024, 0, stream>>>(scores, segs, out);
}